// Round 1
// baseline (803.222 us; speedup 1.0000x reference)
//
#include <hip/hip_runtime.h>
#include <cstddef>

// Problem constants
#define NB 128    // B
#define NT 64     // N0 (time/positions)
#define ND 32     // D0 == D1
#define NG 64     // N1 (groups/capsules)
#define NC 2048   // N1*D1 channels
#define KW 65     // conv kernel size

// ws layout (floats)
#define OFF_URAW 0ull
#define SZ_URAW  (3ull * NB * NT * NC)          // 50331648
#define OFF_F    (OFF_URAW + SZ_URAW)
#define SZ_F     (3ull * NB * NC)               // 786432*3 = 2359296
#define OFF_S1   (OFF_F + SZ_F)
#define SZ_S1    ((unsigned long long)NB * NT)  // 8192
#define OFF_KV   (OFF_S1 + SZ_S1)
#define SZ_KV    ((unsigned long long)NB * NT * NT) // 524288

// ---------------------------------------------------------------------------
// K1: transform. For each j (0..63) a GEMM  [384 rows=(inp,b)] x [32 i] x [2048 c]
// writes u_raw[inp][b][t=j][ch=c]  (ch contiguous -> all downstream reads coalesce)
// grid: j(64) * ntile(16) * inp(3) = 3072 blocks, 256 threads
// ---------------------------------------------------------------------------
__global__ __launch_bounds__(256) void k_transform(
    const float* __restrict__ x1, const float* __restrict__ x2,
    const float* __restrict__ x3, const float* __restrict__ W,
    float* __restrict__ uraw) {
  int bid = blockIdx.x;
  int j   = bid & 63;
  int nt  = (bid >> 6) & 15;
  int inp = bid >> 10;
  const float* x = (inp == 0) ? x1 : ((inp == 1) ? x2 : x3);
  float* uout = uraw + (size_t)inp * ((size_t)NB * NT * NC);

  __shared__ float as[32][132];  // [i][b]
  __shared__ float bs[32][132];  // [i][c_local]
  int tid = threadIdx.x;

  { // A tile: x[b][j][i]  -> as[i][b]
    int b = tid >> 1, h = tid & 1;
    const float* xp = x + ((size_t)b * NT + j) * ND + h * 16;
#pragma unroll
    for (int q = 0; q < 4; ++q) {
      float4 v = *reinterpret_cast<const float4*>(xp + q * 4);
      int i0 = h * 16 + q * 4;
      as[i0 + 0][b] = v.x; as[i0 + 1][b] = v.y;
      as[i0 + 2][b] = v.z; as[i0 + 3][b] = v.w;
    }
  }
  { // B tile: W[k0+kk][j][i][z] -> bs[i][kk*32+z]
    int kk = tid >> 6, u = tid & 63;
    int i = u >> 1, h = u & 1;
    const float* wp = W + (((size_t)(nt * 4 + kk) * NT + j) * ND + i) * ND + h * 16;
#pragma unroll
    for (int q = 0; q < 4; ++q) {
      float4 v = *reinterpret_cast<const float4*>(wp + q * 4);
      int c0 = kk * 32 + h * 16 + q * 4;
      bs[i][c0 + 0] = v.x; bs[i][c0 + 1] = v.y;
      bs[i][c0 + 2] = v.z; bs[i][c0 + 3] = v.w;
    }
  }
  __syncthreads();

  int tm = tid & 15, tn = tid >> 4;
  int m0 = tm * 8, n0 = tn * 8;
  float acc[8][8];
#pragma unroll
  for (int a = 0; a < 8; ++a)
#pragma unroll
    for (int c = 0; c < 8; ++c) acc[a][c] = 0.f;

#pragma unroll 4
  for (int kk = 0; kk < 32; ++kk) {
    float4 a0 = *reinterpret_cast<const float4*>(&as[kk][m0]);
    float4 a1 = *reinterpret_cast<const float4*>(&as[kk][m0 + 4]);
    float4 b0 = *reinterpret_cast<const float4*>(&bs[kk][n0]);
    float4 b1 = *reinterpret_cast<const float4*>(&bs[kk][n0 + 4]);
    float av[8] = {a0.x, a0.y, a0.z, a0.w, a1.x, a1.y, a1.z, a1.w};
    float bv[8] = {b0.x, b0.y, b0.z, b0.w, b1.x, b1.y, b1.z, b1.w};
#pragma unroll
    for (int mi = 0; mi < 8; ++mi)
#pragma unroll
      for (int ni = 0; ni < 8; ++ni)
        acc[mi][ni] = fmaf(av[mi], bv[ni], acc[mi][ni]);
  }

#pragma unroll
  for (int mi = 0; mi < 8; ++mi) {
    float* cp = uout + ((size_t)(m0 + mi) * NT + j) * NC + nt * 128 + n0;
    float4 v0 = {acc[mi][0], acc[mi][1], acc[mi][2], acc[mi][3]};
    float4 v1 = {acc[mi][4], acc[mi][5], acc[mi][6], acc[mi][7]};
    *reinterpret_cast<float4*>(cp)     = v0;
    *reinterpret_cast<float4*>(cp + 4) = v1;
  }
}

// ---------------------------------------------------------------------------
// K2: focus factors f[inp][b][ch] = sqrt(sum_t u'^2) / sqrt(sum_t u'^6)
// where u' = (relu(v)+1e-6)/5.  Focused value = u'^3 * f (applied on the fly later)
// grid: 3*128 blocks, 256 threads
// ---------------------------------------------------------------------------
__global__ __launch_bounds__(256) void k_factors(
    const float* __restrict__ uraw, float* __restrict__ f) {
  int bid = blockIdx.x;  // inp*128 + b
  const float* u = uraw + (size_t)bid * ((size_t)NT * NC);
  int tid = threadIdx.x;
  float s2[8], s6[8];
#pragma unroll
  for (int q = 0; q < 8; ++q) { s2[q] = 0.f; s6[q] = 0.f; }
  for (int t = 0; t < NT; ++t) {
    const float* row = u + (size_t)t * NC;
#pragma unroll
    for (int q = 0; q < 8; ++q) {
      float v = row[tid + q * 256];
      float up = (fmaxf(v, 0.f) + 1e-6f) * 0.2f;
      float p2 = up * up;
      float p3 = p2 * up;
      s2[q] += p2;
      s6[q] += p3 * p3;
    }
  }
#pragma unroll
  for (int q = 0; q < 8; ++q)
    f[(size_t)bid * NC + tid + q * 256] = sqrtf(s2[q]) / sqrtf(s6[q]);
}

// ---------------------------------------------------------------------------
// K3: zero the accumulators (ws is poisoned before every call)
// ---------------------------------------------------------------------------
__global__ void k_zero(float* __restrict__ p, int n) {
  int i = blockIdx.x * blockDim.x + threadIdx.x;
  int stride = gridDim.x * blockDim.x;
  for (; i < n; i += stride) p[i] = 0.f;
}

// ---------------------------------------------------------------------------
// K4: kv[b][t1][t2] = sum_ch u2'[b][ch][t1]*u3'[b][ch][t2]   (focused)
//     s1[b][t]      = sum_ch u1'[b][ch][t]
// grid: b(128) * chq(4) = 512 blocks, 256 threads; atomic reduction
// ---------------------------------------------------------------------------
__global__ __launch_bounds__(256) void k_kv_s1(
    const float* __restrict__ uraw, const float* __restrict__ f,
    float* __restrict__ kv, float* __restrict__ s1) {
  int b = blockIdx.x >> 2, chq = blockIdx.x & 3;
  int chbase = chq * 512;
  const float* u1 = uraw + (size_t)b * ((size_t)NT * NC);
  const float* u2 = u1 + (size_t)NB * NT * NC;
  const float* u3 = u2 + (size_t)NB * NT * NC;
  const float* f1 = f + (size_t)b * NC;
  const float* f2 = f1 + (size_t)NB * NC;
  const float* f3 = f2 + (size_t)NB * NC;

  __shared__ float a2[64][68];   // [ch_local][t1]
  __shared__ float a3[64][68];   // [ch_local][t2]
  __shared__ float red[64][4];
  int tid = threadIdx.x;

  // ---- s1 partial: rows of u1' summed over this block's 512 channels ----
  {
    int t = tid >> 2, cq = tid & 3;
    const float* up = u1 + (size_t)t * NC + chbase + cq * 128;
    const float* fp = f1 + chbase + cq * 128;
    float acc = 0.f;
#pragma unroll 4
    for (int q = 0; q < 32; ++q) {
      float4 v  = *reinterpret_cast<const float4*>(up + q * 4);
      float4 fv = *reinterpret_cast<const float4*>(fp + q * 4);
      float vv[4] = {v.x, v.y, v.z, v.w};
      float ff[4] = {fv.x, fv.y, fv.z, fv.w};
#pragma unroll
      for (int r = 0; r < 4; ++r) {
        float uu = (fmaxf(vv[r], 0.f) + 1e-6f) * 0.2f;
        acc += uu * uu * uu * ff[r];
      }
    }
    red[t][cq] = acc;
  }
  __syncthreads();
  if (tid < 64)
    atomicAdd(&s1[b * NT + tid],
              red[tid][0] + red[tid][1] + red[tid][2] + red[tid][3]);

  // ---- kv partial ----
  int tm = tid & 15, tn = tid >> 4;
  float acc[4][4];
#pragma unroll
  for (int r = 0; r < 4; ++r)
#pragma unroll
    for (int q = 0; q < 4; ++q) acc[r][q] = 0.f;

  for (int tile = 0; tile < 8; ++tile) {
    int ch0 = chbase + tile * 64;
    __syncthreads();
    {
      int t = tid >> 2, c4 = tid & 3;
#pragma unroll
      for (int q = 0; q < 4; ++q) {
        int c = c4 * 16 + q * 4;
        float4 v2 = *reinterpret_cast<const float4*>(u2 + (size_t)t * NC + ch0 + c);
        float4 g2 = *reinterpret_cast<const float4*>(f2 + ch0 + c);
        float4 v3 = *reinterpret_cast<const float4*>(u3 + (size_t)t * NC + ch0 + c);
        float4 g3 = *reinterpret_cast<const float4*>(f3 + ch0 + c);
        float vv2[4] = {v2.x, v2.y, v2.z, v2.w};
        float gg2[4] = {g2.x, g2.y, g2.z, g2.w};
        float vv3[4] = {v3.x, v3.y, v3.z, v3.w};
        float gg3[4] = {g3.x, g3.y, g3.z, g3.w};
#pragma unroll
        for (int r = 0; r < 4; ++r) {
          float uu = (fmaxf(vv2[r], 0.f) + 1e-6f) * 0.2f;
          a2[c + r][t] = uu * uu * uu * gg2[r];
          float ww = (fmaxf(vv3[r], 0.f) + 1e-6f) * 0.2f;
          a3[c + r][t] = ww * ww * ww * gg3[r];
        }
      }
    }
    __syncthreads();
#pragma unroll 8
    for (int ch = 0; ch < 64; ++ch) {
      float4 av = *reinterpret_cast<const float4*>(&a2[ch][tm * 4]);
      float4 bv = *reinterpret_cast<const float4*>(&a3[ch][tn * 4]);
      float aa[4] = {av.x, av.y, av.z, av.w};
      float bb[4] = {bv.x, bv.y, bv.z, bv.w};
#pragma unroll
      for (int r = 0; r < 4; ++r)
#pragma unroll
        for (int q = 0; q < 4; ++q)
          acc[r][q] = fmaf(aa[r], bb[q], acc[r][q]);
    }
  }
#pragma unroll
  for (int r = 0; r < 4; ++r)
#pragma unroll
    for (int q = 0; q < 4; ++q)
      atomicAdd(&kv[(size_t)b * (NT * NT) + (tm * 4 + r) * NT + tn * 4 + q],
                acc[r][q]);
}

// ---------------------------------------------------------------------------
// K5: per (b, g):  z -> x rows -> prefix sums -> conv window sums -> squash
// grid: g(64) * bp(64) blocks (g-major for conv_w L2 reuse), 256 threads,
// each block does 2 consecutive b
// ---------------------------------------------------------------------------
__global__ __launch_bounds__(256) void k_final(
    const float* __restrict__ uraw, const float* __restrict__ f,
    const float* __restrict__ kvg, const float* __restrict__ s1g,
    const float* __restrict__ cw, const float* __restrict__ cb,
    float* __restrict__ out) {
  int g = blockIdx.x >> 6, bp = blockIdx.x & 63;
  int tid = threadIdx.x;

  __shared__ float kvL[64][68];
  __shared__ float s1L[64];
  __shared__ float utL[64][36];   // [t][ci]  focused u1 tile
  __shared__ float xrL[32][68];   // [ci][t]
  __shared__ float preL[32][68];  // prefix sums, [ci][0..64]
  __shared__ float SL[32][68];    // window sums, [ci][k 0..64]
  __shared__ float zL[32];
  __shared__ float partL[32][8];

  for (int bi = 0; bi < 2; ++bi) {
    int b = bp * 2 + bi;
    __syncthreads();

    // stage kv[b], s1[b]
#pragma unroll
    for (int q = 0; q < 16; ++q) {
      int i = tid + q * 256;
      kvL[i >> 6][i & 63] = kvg[(size_t)b * (NT * NT) + i];
    }
    if (tid < 64) s1L[tid] = s1g[b * NT + tid];

    // stage focused u1 tile: ut[t][ci] = u1'[b][g*32+ci][t]
    {
      int t = tid >> 2, c4 = tid & 3;
      const float* up = uraw + ((size_t)b * NT + t) * NC + g * 32 + c4 * 8;
      const float* fp = f + (size_t)b * NC + g * 32 + c4 * 8;
#pragma unroll
      for (int q = 0; q < 2; ++q) {
        float4 v  = *reinterpret_cast<const float4*>(up + q * 4);
        float4 fv = *reinterpret_cast<const float4*>(fp + q * 4);
        float vv[4] = {v.x, v.y, v.z, v.w};
        float ff[4] = {fv.x, fv.y, fv.z, fv.w};
#pragma unroll
        for (int r = 0; r < 4; ++r) {
          float uu = (fmaxf(vv[r], 0.f) + 1e-6f) * 0.2f;
          utL[t][c4 * 8 + q * 4 + r] = uu * uu * uu * ff[r];
        }
      }
    }
    __syncthreads();

    // z[ci] = 1 / (dot(u1'[ci], s1) + eps)
    if (tid < 32) {
      float acc = 0.f;
      for (int t = 0; t < NT; ++t) acc += utL[t][tid] * s1L[t];
      zL[tid] = 1.f / (acc + 1.1920928955078125e-07f);
    }
    __syncthreads();

    // x rows: xr[ci][t2] = z[ci] * sum_t1 ut[t1][ci] * kv[t1][t2]
    {
      int ci = tid >> 3, tg = tid & 7;
      float acc[8];
#pragma unroll
      for (int r = 0; r < 8; ++r) acc[r] = 0.f;
#pragma unroll 8
      for (int t1 = 0; t1 < NT; ++t1) {
        float a = utL[t1][ci];
        float4 k0 = *reinterpret_cast<const float4*>(&kvL[t1][tg * 8]);
        float4 k1 = *reinterpret_cast<const float4*>(&kvL[t1][tg * 8 + 4]);
        acc[0] = fmaf(a, k0.x, acc[0]); acc[1] = fmaf(a, k0.y, acc[1]);
        acc[2] = fmaf(a, k0.z, acc[2]); acc[3] = fmaf(a, k0.w, acc[3]);
        acc[4] = fmaf(a, k1.x, acc[4]); acc[5] = fmaf(a, k1.y, acc[5]);
        acc[6] = fmaf(a, k1.z, acc[6]); acc[7] = fmaf(a, k1.w, acc[7]);
      }
      float z = zL[ci];
#pragma unroll
      for (int r = 0; r < 8; ++r) xrL[ci][tg * 8 + r] = acc[r] * z;
    }
    __syncthreads();

    // prefix sums per row
    if (tid < 32) {
      float run = 0.f;
      preL[tid][0] = 0.f;
      for (int t = 0; t < NT; ++t) {
        run += xrL[tid][t];
        preL[tid][t + 1] = run;
      }
    }
    __syncthreads();

    // window sums S[ci][k], k=0..64, d=k-32:
    //   d>=0: total - pre[d];   d<0: pre[64+d]
    for (int idx = tid; idx < 32 * 65; idx += 256) {
      int ci = idx / 65;
      int k = idx - ci * 65;
      int d = k - 32;
      SL[ci][k] = (d >= 0) ? (preL[ci][64] - preL[ci][d]) : preL[ci][64 + d];
    }
    __syncthreads();

    // conv window-sum: ysum[o] = sum_{ci,k} cw[g*32+o][ci][k] * S[ci][k]
    {
      int o = tid >> 3, p = tid & 7;
      const float* cwp = cw + (size_t)(g * 32 + o) * (32 * KW);
      float acc = 0.f;
      for (int ci = 0; ci < 32; ++ci) {
        const float* row = cwp + ci * KW + p * 8;
#pragma unroll
        for (int r = 0; r < 8; ++r) acc += row[r] * SL[ci][p * 8 + r];
      }
      if (p == 0) {
        for (int ci = 0; ci < 32; ++ci) acc += cwp[ci * KW + 64] * SL[ci][64];
      }
      partL[o][p] = acc;
    }
    __syncthreads();

    // reduce, add xsum + bias, squash over the 32-wide group, store
    if (tid < 32) {
      int o = tid;
      float y = 0.f;
#pragma unroll
      for (int p = 0; p < 8; ++p) y += partL[o][p];
      float val = preL[o][64] + y + 64.f * cb[g * 32 + o];
      float sq = val * val;
#pragma unroll
      for (int m = 16; m >= 1; m >>= 1) sq += __shfl_xor(sq, m, 32);
      float norm = sqrtf(sq);
      float coef = 1.f - 1.f / (expf(norm) + 1e-20f);
      out[((size_t)b * NG + g) * ND + o] = coef * val / (norm + 1e-20f);
    }
  }
}

// ---------------------------------------------------------------------------
extern "C" void kernel_launch(void* const* d_in, const int* in_sizes, int n_in,
                              void* d_out, int out_size, void* d_ws, size_t ws_size,
                              hipStream_t stream) {
  const float* x1 = (const float*)d_in[0];
  const float* x2 = (const float*)d_in[1];
  const float* x3 = (const float*)d_in[2];
  const float* W  = (const float*)d_in[3];
  const float* cw = (const float*)d_in[4];
  const float* cb = (const float*)d_in[5];
  float* out = (float*)d_out;

  float* ws   = (float*)d_ws;
  float* uraw = ws + OFF_URAW;
  float* f    = ws + OFF_F;
  float* s1   = ws + OFF_S1;
  float* kv   = ws + OFF_KV;

  k_transform<<<3072, 256, 0, stream>>>(x1, x2, x3, W, uraw);
  k_factors<<<384, 256, 0, stream>>>(uraw, f);
  k_zero<<<512, 256, 0, stream>>>(s1, (int)(SZ_S1 + SZ_KV));
  k_kv_s1<<<512, 256, 0, stream>>>(uraw, f, kv, s1);
  k_final<<<4096, 256, 0, stream>>>(uraw, f, kv, s1, cw, cb, out);
}

// Round 4
// 361.637 us; speedup vs baseline: 2.2211x; 2.2211x over previous
//
#include <hip/hip_runtime.h>
#include <cstddef>

// Problem constants
#define NB 128    // B
#define NT 64     // N0 (time/positions)
#define ND 32     // D0 == D1
#define NG 64     // N1 (groups/capsules)
#define NC 2048   // N1*D1 channels
#define KW 65     // conv kernel size
#define EPSZ 1.1920928955078125e-07f

// ws layout (floats)
#define OFF_URAW 0ull
#define SZ_URAW  (3ull * NB * NT * NC)
#define OFF_F    (OFF_URAW + SZ_URAW)
#define SZ_F     (3ull * NB * NC)
#define OFF_S1   (OFF_F + SZ_F)
#define SZ_S1    ((unsigned long long)NB * NT)
#define OFF_KV   (OFF_S1 + SZ_S1)
#define SZ_KV    ((unsigned long long)NB * NT * NT)
// pre[b][ch][jj0..63] overlays the (dead-after-k_kv_s1) u2 region
// cwt[o][ci*64+jj]    overlays the u3 region

// ---------------------------------------------------------------------------
// K1: transform. For each j (0..63) a GEMM  [384 rows=(inp,b)] x [32 i] x [2048 c]
// writes u_raw[inp][b][t=j][ch=c]
// ---------------------------------------------------------------------------
__global__ __launch_bounds__(256) void k_transform(
    const float* __restrict__ x1, const float* __restrict__ x2,
    const float* __restrict__ x3, const float* __restrict__ W,
    float* __restrict__ uraw) {
  int bid = blockIdx.x;
  int j   = bid & 63;
  int nt  = (bid >> 6) & 15;
  int inp = bid >> 10;
  const float* x = (inp == 0) ? x1 : ((inp == 1) ? x2 : x3);
  float* uout = uraw + (size_t)inp * ((size_t)NB * NT * NC);

  __shared__ float as[32][132];  // [i][b]
  __shared__ float bs[32][132];  // [i][c_local]
  int tid = threadIdx.x;

  { // A tile: x[b][j][i]  -> as[i][b]
    int b = tid >> 1, h = tid & 1;
    const float* xp = x + ((size_t)b * NT + j) * ND + h * 16;
#pragma unroll
    for (int q = 0; q < 4; ++q) {
      float4 v = *reinterpret_cast<const float4*>(xp + q * 4);
      int i0 = h * 16 + q * 4;
      as[i0 + 0][b] = v.x; as[i0 + 1][b] = v.y;
      as[i0 + 2][b] = v.z; as[i0 + 3][b] = v.w;
    }
  }
  { // B tile: W[k0+kk][j][i][z] -> bs[i][kk*32+z]
    int kk = tid >> 6, u = tid & 63;
    int i = u >> 1, h = u & 1;
    const float* wp = W + (((size_t)(nt * 4 + kk) * NT + j) * ND + i) * ND + h * 16;
#pragma unroll
    for (int q = 0; q < 4; ++q) {
      float4 v = *reinterpret_cast<const float4*>(wp + q * 4);
      int c0 = kk * 32 + h * 16 + q * 4;
      bs[i][c0 + 0] = v.x; bs[i][c0 + 1] = v.y;
      bs[i][c0 + 2] = v.z; bs[i][c0 + 3] = v.w;
    }
  }
  __syncthreads();

  int tm = tid & 15, tn = tid >> 4;
  int m0 = tm * 8, n0 = tn * 8;
  float acc[8][8];
#pragma unroll
  for (int a = 0; a < 8; ++a)
#pragma unroll
    for (int c = 0; c < 8; ++c) acc[a][c] = 0.f;

#pragma unroll 4
  for (int kk = 0; kk < 32; ++kk) {
    float4 a0 = *reinterpret_cast<const float4*>(&as[kk][m0]);
    float4 a1 = *reinterpret_cast<const float4*>(&as[kk][m0 + 4]);
    float4 b0 = *reinterpret_cast<const float4*>(&bs[kk][n0]);
    float4 b1 = *reinterpret_cast<const float4*>(&bs[kk][n0 + 4]);
    float av[8] = {a0.x, a0.y, a0.z, a0.w, a1.x, a1.y, a1.z, a1.w};
    float bv[8] = {b0.x, b0.y, b0.z, b0.w, b1.x, b1.y, b1.z, b1.w};
#pragma unroll
    for (int mi = 0; mi < 8; ++mi)
#pragma unroll
      for (int ni = 0; ni < 8; ++ni)
        acc[mi][ni] = fmaf(av[mi], bv[ni], acc[mi][ni]);
  }

#pragma unroll
  for (int mi = 0; mi < 8; ++mi) {
    float* cp = uout + ((size_t)(m0 + mi) * NT + j) * NC + nt * 128 + n0;
    float4 v0 = {acc[mi][0], acc[mi][1], acc[mi][2], acc[mi][3]};
    float4 v1 = {acc[mi][4], acc[mi][5], acc[mi][6], acc[mi][7]};
    *reinterpret_cast<float4*>(cp)     = v0;
    *reinterpret_cast<float4*>(cp + 4) = v1;
  }
}

// ---------------------------------------------------------------------------
// K2: focus factors f[inp][b][ch] = sqrt(sum_t u'^2) / sqrt(sum_t u'^6)
// ---------------------------------------------------------------------------
__global__ __launch_bounds__(256) void k_factors(
    const float* __restrict__ uraw, float* __restrict__ f) {
  int bid = blockIdx.x;  // inp*128 + b
  const float* u = uraw + (size_t)bid * ((size_t)NT * NC);
  int tid = threadIdx.x;
  float s2[8], s6[8];
#pragma unroll
  for (int q = 0; q < 8; ++q) { s2[q] = 0.f; s6[q] = 0.f; }
  for (int t = 0; t < NT; ++t) {
    const float* row = u + (size_t)t * NC;
#pragma unroll
    for (int q = 0; q < 8; ++q) {
      float v = row[tid + q * 256];
      float up = (fmaxf(v, 0.f) + 1e-6f) * 0.2f;
      float p2 = up * up;
      float p3 = p2 * up;
      s2[q] += p2;
      s6[q] += p3 * p3;
    }
  }
#pragma unroll
  for (int q = 0; q < 8; ++q)
    f[(size_t)bid * NC + tid + q * 256] = sqrtf(s2[q]) / sqrtf(s6[q]);
}

// ---------------------------------------------------------------------------
// K3: zero the accumulators
// ---------------------------------------------------------------------------
__global__ void k_zero(float* __restrict__ p, int n) {
  int i = blockIdx.x * blockDim.x + threadIdx.x;
  int stride = gridDim.x * blockDim.x;
  for (; i < n; i += stride) p[i] = 0.f;
}

// ---------------------------------------------------------------------------
// K4: kv[b][t1][t2] = sum_ch u2'[t1]*u3'[t2];  s1[b][t] = sum_ch u1'[t]
// ---------------------------------------------------------------------------
__global__ __launch_bounds__(256) void k_kv_s1(
    const float* __restrict__ uraw, const float* __restrict__ f,
    float* __restrict__ kv, float* __restrict__ s1) {
  int b = blockIdx.x >> 2, chq = blockIdx.x & 3;
  int chbase = chq * 512;
  const float* u1 = uraw + (size_t)b * ((size_t)NT * NC);
  const float* u2 = u1 + (size_t)NB * NT * NC;
  const float* u3 = u2 + (size_t)NB * NT * NC;
  const float* f1 = f + (size_t)b * NC;
  const float* f2 = f1 + (size_t)NB * NC;
  const float* f3 = f2 + (size_t)NB * NC;

  __shared__ float a2[64][68];
  __shared__ float a3[64][68];
  __shared__ float red[64][4];
  int tid = threadIdx.x;

  {
    int t = tid >> 2, cq = tid & 3;
    const float* up = u1 + (size_t)t * NC + chbase + cq * 128;
    const float* fp = f1 + chbase + cq * 128;
    float acc = 0.f;
#pragma unroll 4
    for (int q = 0; q < 32; ++q) {
      float4 v  = *reinterpret_cast<const float4*>(up + q * 4);
      float4 fv = *reinterpret_cast<const float4*>(fp + q * 4);
      float vv[4] = {v.x, v.y, v.z, v.w};
      float ff[4] = {fv.x, fv.y, fv.z, fv.w};
#pragma unroll
      for (int r = 0; r < 4; ++r) {
        float uu = (fmaxf(vv[r], 0.f) + 1e-6f) * 0.2f;
        acc += uu * uu * uu * ff[r];
      }
    }
    red[t][cq] = acc;
  }
  __syncthreads();
  if (tid < 64)
    atomicAdd(&s1[b * NT + tid],
              red[tid][0] + red[tid][1] + red[tid][2] + red[tid][3]);

  int tm = tid & 15, tn = tid >> 4;
  float acc[4][4];
#pragma unroll
  for (int r = 0; r < 4; ++r)
#pragma unroll
    for (int q = 0; q < 4; ++q) acc[r][q] = 0.f;

  for (int tile = 0; tile < 8; ++tile) {
    int ch0 = chbase + tile * 64;
    __syncthreads();
    {
      int t = tid >> 2, c4 = tid & 3;
#pragma unroll
      for (int q = 0; q < 4; ++q) {
        int c = c4 * 16 + q * 4;
        float4 v2 = *reinterpret_cast<const float4*>(u2 + (size_t)t * NC + ch0 + c);
        float4 g2 = *reinterpret_cast<const float4*>(f2 + ch0 + c);
        float4 v3 = *reinterpret_cast<const float4*>(u3 + (size_t)t * NC + ch0 + c);
        float4 g3 = *reinterpret_cast<const float4*>(f3 + ch0 + c);
        float vv2[4] = {v2.x, v2.y, v2.z, v2.w};
        float gg2[4] = {g2.x, g2.y, g2.z, g2.w};
        float vv3[4] = {v3.x, v3.y, v3.z, v3.w};
        float gg3[4] = {g3.x, g3.y, g3.z, g3.w};
#pragma unroll
        for (int r = 0; r < 4; ++r) {
          float uu = (fmaxf(vv2[r], 0.f) + 1e-6f) * 0.2f;
          a2[c + r][t] = uu * uu * uu * gg2[r];
          float ww = (fmaxf(vv3[r], 0.f) + 1e-6f) * 0.2f;
          a3[c + r][t] = ww * ww * ww * gg3[r];
        }
      }
    }
    __syncthreads();
#pragma unroll 8
    for (int ch = 0; ch < 64; ++ch) {
      float4 av = *reinterpret_cast<const float4*>(&a2[ch][tm * 4]);
      float4 bv = *reinterpret_cast<const float4*>(&a3[ch][tn * 4]);
      float aa[4] = {av.x, av.y, av.z, av.w};
      float bb[4] = {bv.x, bv.y, bv.z, bv.w};
#pragma unroll
      for (int r = 0; r < 4; ++r)
#pragma unroll
        for (int q = 0; q < 4; ++q)
          acc[r][q] = fmaf(aa[r], bb[q], acc[r][q]);
    }
  }
#pragma unroll
  for (int r = 0; r < 4; ++r)
#pragma unroll
    for (int q = 0; q < 4; ++q)
      atomicAdd(&kv[(size_t)b * (NT * NT) + (tm * 4 + r) * NT + tn * 4 + q],
                acc[r][q]);
}

// ---------------------------------------------------------------------------
// K5: conv-weight transform.  ysum[o] = sum_{ci,jj} cwt[o][ci][jj] * pre[ci][jj]
// where pre index jj holds prefix at j=jj+1.  Derivation:
//   ysum = sum_{k>=32} cw[k]*(pre64 - pre[k-32]) + sum_{k<32} cw[k]*pre[k+32]
// grid 2048 blocks (one per out-channel) x 64 threads (one per jj)
// ---------------------------------------------------------------------------
__global__ __launch_bounds__(64) void k_cwt(
    const float* __restrict__ cw, float* __restrict__ cwt) {
  int o = blockIdx.x;
  int tid = threadIdx.x;
  __shared__ float row[32 * KW];
  for (int i = tid; i < 32 * KW; i += 64) row[i] = cw[(size_t)o * (32 * KW) + i];
  __syncthreads();
  int jj = tid, j = jj + 1;
  for (int ci = 0; ci < 32; ++ci) {
    float v = 0.f;
    if (j <= 32) v -= row[ci * KW + j + 32];
    if (j >= 32 && j <= 63) v += row[ci * KW + j - 32];
    if (j == 64) {
      float s = 0.f;
      for (int k = 32; k <= 64; ++k) s += row[ci * KW + k];
      v += s;
    }
    cwt[(size_t)o * 2048 + ci * 64 + jj] = v;
  }
}

// ---------------------------------------------------------------------------
// K6: pre[b][ch][jj] = z[b,ch] * sum_t1 ut[t1,ch] * kvpre[t1][jj]
// kvpre = prefix of kv along t2 (computed once per block in LDS).
// z folded into the same loop via an extra FMA against s1.
// grid: b(128) x quarter(4) = 512 blocks, 256 threads, 4ci x 8j register tile
// ---------------------------------------------------------------------------
__global__ __launch_bounds__(256) void k_pre(
    const float* __restrict__ uraw, const float* __restrict__ f,
    const float* __restrict__ kvg, const float* __restrict__ s1g,
    float* __restrict__ pre) {
  int b = blockIdx.x >> 2, q = blockIdx.x & 3;
  int chbase = q * 512;
  const float* u1 = uraw + (size_t)b * ((size_t)NT * NC);
  const float* f1 = f + (size_t)b * NC;
  int tid = threadIdx.x;

  __shared__ float kvpreL[64][68];
  __shared__ float s1L[64];
  __shared__ float utL[64][132];   // [t][c4-skewed ch_local], skew c4*33

#pragma unroll
  for (int qq = 0; qq < 16; ++qq) {
    int i = tid + qq * 256;
    kvpreL[i >> 6][i & 63] = kvg[(size_t)b * (NT * NT) + i];
  }
  if (tid < 64) s1L[tid] = s1g[b * NT + tid];
  __syncthreads();
  if (tid < 64) {  // prefix each kv row: kvpreL[t1][jj] = sum_{t2<=jj} kv[t1][t2]
    float run = 0.f;
    for (int t2 = 0; t2 < 64; ++t2) {
      run += kvpreL[tid][t2];
      kvpreL[tid][t2] = run;
    }
  }

  int cg = tid >> 3, tg = tid & 7;   // cg: 4-ch group, tg: 8-j group
  for (int tile = 0; tile < 4; ++tile) {
    int ch0 = chbase + tile * 128;
    __syncthreads();
    { // stage focused u1: utL[t][c4*33 + w] = u1'[b][ch0 + c4*32 + w][t]
      int t = tid >> 2, c4 = tid & 3;
      const float* up = u1 + (size_t)t * NC + ch0 + c4 * 32;
      const float* fp = f1 + ch0 + c4 * 32;
#pragma unroll
      for (int qq = 0; qq < 8; ++qq) {
        float4 v  = *reinterpret_cast<const float4*>(up + qq * 4);
        float4 fv = *reinterpret_cast<const float4*>(fp + qq * 4);
        float vv[4] = {v.x, v.y, v.z, v.w};
        float ff[4] = {fv.x, fv.y, fv.z, fv.w};
#pragma unroll
        for (int r = 0; r < 4; ++r) {
          float uu = (fmaxf(vv[r], 0.f) + 1e-6f) * 0.2f;
          utL[t][c4 * 33 + qq * 4 + r] = uu * uu * uu * ff[r];
        }
      }
    }
    __syncthreads();

    // compute: channels cl = cg*4 + r (r=0..3), j-cols tg*8 .. tg*8+7
    int cl = cg * 4;
    int sk = (cl >> 5) * 33 + (cl & 31);  // skewed base (cl..cl+3 contiguous)
    float acc[4][8];
#pragma unroll
    for (int r = 0; r < 4; ++r)
#pragma unroll
      for (int c = 0; c < 8; ++c) acc[r][c] = 0.f;
    float accz[4] = {0.f, 0.f, 0.f, 0.f};

#pragma unroll 4
    for (int t1 = 0; t1 < 64; ++t1) {
      float4 a = *reinterpret_cast<const float4*>(&utL[t1][sk]);
      float s = s1L[t1];
      float4 k0 = *reinterpret_cast<const float4*>(&kvpreL[t1][tg * 8]);
      float4 k1 = *reinterpret_cast<const float4*>(&kvpreL[t1][tg * 8 + 4]);
      float aa[4] = {a.x, a.y, a.z, a.w};
      float kk[8] = {k0.x, k0.y, k0.z, k0.w, k1.x, k1.y, k1.z, k1.w};
#pragma unroll
      for (int r = 0; r < 4; ++r) {
        accz[r] = fmaf(aa[r], s, accz[r]);
#pragma unroll
        for (int c = 0; c < 8; ++c)
          acc[r][c] = fmaf(aa[r], kk[c], acc[r][c]);
      }
    }
#pragma unroll
    for (int r = 0; r < 4; ++r) {
      float z = 1.f / (accz[r] + EPSZ);
      float* pp = pre + ((size_t)b * NC + ch0 + cl + r) * 64 + tg * 8;
      float4 o0 = {acc[r][0] * z, acc[r][1] * z, acc[r][2] * z, acc[r][3] * z};
      float4 o1 = {acc[r][4] * z, acc[r][5] * z, acc[r][6] * z, acc[r][7] * z};
      *reinterpret_cast<float4*>(pp)     = o0;
      *reinterpret_cast<float4*>(pp + 4) = o1;
    }
  }
}

// ---------------------------------------------------------------------------
// K7: per-g GEMM  ysum[b][o] = sum_{K=2048} cwt[g*32+o][K] * pre[b][g*32..][K]
// + xsum (= pre at jj=63 of channel o) + bias, then squash over o, store.
// grid: g(64) x bq(4) = 256 blocks (g-major for cwt L2 reuse), 256 threads,
// 2b x 2o register tile.
// ---------------------------------------------------------------------------
__global__ __launch_bounds__(256) void k_gemm(
    const float* __restrict__ pre, const float* __restrict__ cwt,
    const float* __restrict__ cb, float* __restrict__ out) {
  int g = blockIdx.x >> 2, bq = blockIdx.x & 3;
  int b0 = bq * 32;
  int tid = threadIdx.x;
  int oh = tid & 15, bh = tid >> 4;   // o in {oh, oh+16}, b_local in {bh, bh+16}

  __shared__ float preL[32][68];
  __shared__ float cwtL[32][68];

  float a00 = 0.f, a01 = 0.f, a10 = 0.f, a11 = 0.f;
  float xs00 = 0.f, xs01 = 0.f, xs10 = 0.f, xs11 = 0.f;

  for (int kc = 0; kc < 32; ++kc) {
    __syncthreads();
    { // stage: 8 floats per thread each
      int r8 = tid >> 3, s8 = tid & 7;
      const float* ps = pre + ((size_t)(b0 + r8) * NC + g * 32) * 64 + kc * 64 + s8 * 8;
      float4 p0 = *reinterpret_cast<const float4*>(ps);
      float4 p1 = *reinterpret_cast<const float4*>(ps + 4);
      *reinterpret_cast<float4*>(&preL[r8][s8 * 8])     = p0;
      *reinterpret_cast<float4*>(&preL[r8][s8 * 8 + 4]) = p1;
      const float* cs = cwt + (size_t)(g * 32 + r8) * 2048 + kc * 64 + s8 * 8;
      float4 c0 = *reinterpret_cast<const float4*>(cs);
      float4 c1 = *reinterpret_cast<const float4*>(cs + 4);
      *reinterpret_cast<float4*>(&cwtL[r8][s8 * 8])     = c0;
      *reinterpret_cast<float4*>(&cwtL[r8][s8 * 8 + 4]) = c1;
    }
    __syncthreads();

    if (kc == oh)      { xs00 = preL[bh][63]; xs10 = preL[bh + 16][63]; }
    if (kc == oh + 16) { xs01 = preL[bh][63]; xs11 = preL[bh + 16][63]; }

#pragma unroll
    for (int kk = 0; kk < 64; kk += 4) {
      float4 p0 = *reinterpret_cast<const float4*>(&preL[bh][kk]);
      float4 p1 = *reinterpret_cast<const float4*>(&preL[bh + 16][kk]);
      float4 c0 = *reinterpret_cast<const float4*>(&cwtL[oh][kk]);
      float4 c1 = *reinterpret_cast<const float4*>(&cwtL[oh + 16][kk]);
      a00 = fmaf(p0.x, c0.x, a00); a00 = fmaf(p0.y, c0.y, a00);
      a00 = fmaf(p0.z, c0.z, a00); a00 = fmaf(p0.w, c0.w, a00);
      a01 = fmaf(p0.x, c1.x, a01); a01 = fmaf(p0.y, c1.y, a01);
      a01 = fmaf(p0.z, c1.z, a01); a01 = fmaf(p0.w, c1.w, a01);
      a10 = fmaf(p1.x, c0.x, a10); a10 = fmaf(p1.y, c0.y, a10);
      a10 = fmaf(p1.z, c0.z, a10); a10 = fmaf(p1.w, c0.w, a10);
      a11 = fmaf(p1.x, c1.x, a11); a11 = fmaf(p1.y, c1.y, a11);
      a11 = fmaf(p1.z, c1.z, a11); a11 = fmaf(p1.w, c1.w, a11);
    }
  }

  float cb0 = cb[g * 32 + oh], cb1 = cb[g * 32 + oh + 16];
  float v00 = a00 + xs00 + 64.f * cb0;   // (b=bh,    o=oh)
  float v01 = a01 + xs01 + 64.f * cb1;   // (b=bh,    o=oh+16)
  float v10 = a10 + xs10 + 64.f * cb0;   // (b=bh+16, o=oh)
  float v11 = a11 + xs11 + 64.f * cb1;   // (b=bh+16, o=oh+16)

  float sqA = v00 * v00 + v01 * v01;
  float sqB = v10 * v10 + v11 * v11;
#pragma unroll
  for (int m = 8; m >= 1; m >>= 1) {
    sqA += __shfl_xor(sqA, m, 16);
    sqB += __shfl_xor(sqB, m, 16);
  }
  float nA = sqrtf(sqA), nB = sqrtf(sqB);
  float cA = 1.f - 1.f / (expf(nA) + 1e-20f);
  float cB = 1.f - 1.f / (expf(nB) + 1e-20f);
  float iA = cA / (nA + 1e-20f), iB = cB / (nB + 1e-20f);

  size_t baseA = ((size_t)(b0 + bh) * NG + g) * ND;
  size_t baseB = ((size_t)(b0 + bh + 16) * NG + g) * ND;
  out[baseA + oh]      = v00 * iA;
  out[baseA + oh + 16] = v01 * iA;
  out[baseB + oh]      = v10 * iB;
  out[baseB + oh + 16] = v11 * iB;
}

// ---------------------------------------------------------------------------
extern "C" void kernel_launch(void* const* d_in, const int* in_sizes, int n_in,
                              void* d_out, int out_size, void* d_ws, size_t ws_size,
                              hipStream_t stream) {
  const float* x1 = (const float*)d_in[0];
  const float* x2 = (const float*)d_in[1];
  const float* x3 = (const float*)d_in[2];
  const float* W  = (const float*)d_in[3];
  const float* cw = (const float*)d_in[4];
  const float* cb = (const float*)d_in[5];
  float* out = (float*)d_out;

  float* ws   = (float*)d_ws;
  float* uraw = ws + OFF_URAW;
  float* f    = ws + OFF_F;
  float* s1   = ws + OFF_S1;
  float* kv   = ws + OFF_KV;
  // overlays (dead after k_kv_s1):
  float* pre  = uraw + (size_t)NB * NT * NC;        // u2 region, 16.8M floats
  float* cwt  = uraw + 2ull * NB * NT * NC;         // u3 region, 4.2M floats

  k_transform<<<3072, 256, 0, stream>>>(x1, x2, x3, W, uraw);
  k_factors<<<384, 256, 0, stream>>>(uraw, f);
  k_zero<<<512, 256, 0, stream>>>(s1, (int)(SZ_S1 + SZ_KV));
  k_kv_s1<<<512, 256, 0, stream>>>(uraw, f, kv, s1);
  k_cwt<<<2048, 64, 0, stream>>>(cw, cwt);
  k_pre<<<512, 256, 0, stream>>>(uraw, f, kv, s1, pre);
  k_gemm<<<256, 256, 0, stream>>>(pre, cwt, cb, out);
}